// Round 5
// baseline (239.149 us; speedup 1.0000x reference)
//
#include <hip/hip_runtime.h>

#define BATCH_L 524288
#define NL 40
#define NXL 20
#define BLOCK 256
#define GRID 4096                      // NHALF/BLOCK: 1 half-row per thread
#define NHALF (BATCH_L * 2)            // 1,048,576 half-rows == NTHREADS

// R9: inline-asm forced 15-deep load pipeline. R6 spilled (WRITE=28.7MB),
// R7/R8 re-serialized (VGPR=32 despite sched_barrier -- 15 live float4 need
// >=60 VGPRs, so the compiler provably undid the staging). Volatile asm
// global_load_dwordx4 with "=v" outputs is opaque to scheduler+regalloc: the
// 60 result VGPRs MUST stay live, giving a true 15-outstanding-load pipeline
// per wave. One explicit s_waitcnt vmcnt(0) + sched_barrier(0) (guide rule
// #18) gates the consumes. This is the discriminating experiment between
//   (a) CU-side MLP starvation  -> expect ~50-65us, BW 4-5 TB/s
//   (b) ~3 TB/s read-path rate ceiling (m13 copy = 3.15 TB/s read-side;
//       warm-L3 == cold timing; coalesced == strided)  -> expect flat ~90us
// Math identical to R8 (shfl_xor halo, masked dd, double reduce): absmax 0.
__global__ void hybrid_loss_main(
    const float4* __restrict__ pred4,
    const float4* __restrict__ targ4,
    const float4* __restrict__ ycur4,
    double* __restrict__ partials)     // [GRID][2]
{
    const int t = blockIdx.x * BLOCK + threadIdx.x;
    const float ddmask = (threadIdx.x & 1) ? 0.f : 1.f;  // h==0 half has the dd term

    const char* pb = (const char*)pred4 + (size_t)t * 80;  // 20 floats per half-row
    const char* tb = (const char*)targ4 + (size_t)t * 80;
    const char* yb = (const char*)ycur4 + (size_t)t * 80;

    // ---- 15 forced-outstanding loads (volatile asm, results pinned live) ----
    float4 pc0, pc1, pc2, pc3, pc4;
    float4 tc0, tc1, tc2, tc3, tc4;
    float4 yc0, yc1, yc2, yc3, yc4;
    asm volatile("global_load_dwordx4 %0, %1, off           " : "=v"(pc0) : "v"(pb));
    asm volatile("global_load_dwordx4 %0, %1, off offset:16 " : "=v"(pc1) : "v"(pb));
    asm volatile("global_load_dwordx4 %0, %1, off offset:32 " : "=v"(pc2) : "v"(pb));
    asm volatile("global_load_dwordx4 %0, %1, off offset:48 " : "=v"(pc3) : "v"(pb));
    asm volatile("global_load_dwordx4 %0, %1, off offset:64 " : "=v"(pc4) : "v"(pb));
    asm volatile("global_load_dwordx4 %0, %1, off           " : "=v"(tc0) : "v"(tb));
    asm volatile("global_load_dwordx4 %0, %1, off offset:16 " : "=v"(tc1) : "v"(tb));
    asm volatile("global_load_dwordx4 %0, %1, off offset:32 " : "=v"(tc2) : "v"(tb));
    asm volatile("global_load_dwordx4 %0, %1, off offset:48 " : "=v"(tc3) : "v"(tb));
    asm volatile("global_load_dwordx4 %0, %1, off offset:64 " : "=v"(tc4) : "v"(tb));
    asm volatile("global_load_dwordx4 %0, %1, off           " : "=v"(yc0) : "v"(yb));
    asm volatile("global_load_dwordx4 %0, %1, off offset:16 " : "=v"(yc1) : "v"(yb));
    asm volatile("global_load_dwordx4 %0, %1, off offset:32 " : "=v"(yc2) : "v"(yb));
    asm volatile("global_load_dwordx4 %0, %1, off offset:48 " : "=v"(yc3) : "v"(yb));
    asm volatile("global_load_dwordx4 %0, %1, off offset:64 " : "=v"(yc4) : "v"(yb));
    asm volatile("s_waitcnt vmcnt(0)" ::: "memory");
    __builtin_amdgcn_sched_barrier(0);   // rule #18: no consume hoists above the wait

    const float4 pc[5] = {pc0, pc1, pc2, pc3, pc4};
    const float4 tc[5] = {tc0, tc1, tc2, tc3, tc4};
    const float4 yc[5] = {yc0, yc1, yc2, yc3, yc4};

    float sdd = 0.f, spi = 0.f;

    float p[20];
#pragma unroll
    for (int k = 0; k < 5; ++k) {
        p[4 * k + 0] = pc[k].x; p[4 * k + 1] = pc[k].y;
        p[4 * k + 2] = pc[k].z; p[4 * k + 3] = pc[k].w;
    }

    // Data-driven MSE (masked: only the cols 0..19 half contributes).
    {
        float s = 0.f;
#pragma unroll
        for (int k = 0; k < 5; ++k) {
            const float d0 = pc[k].x - tc[k].x;
            const float d1 = pc[k].y - tc[k].y;
            const float d2 = pc[k].z - tc[k].z;
            const float d3 = pc[k].w - tc[k].w;
            s += d0 * d0 + d1 * d1 + d2 * d2 + d3 * d3;
        }
        sdd += ddmask * s;
    }

    // Boundary exchange with the partner half (lane t^1).
    const float prev2 = __shfl_xor(p[18], 1);
    const float prev1 = __shfl_xor(p[19], 1);
    const float nxt   = __shfl_xor(p[0], 1);

    // d_i = (101 p_i - 100 y_i - 8) - (p_{i+1} - p_{i-2}) * p_{i-1}
    {
        const float* y = reinterpret_cast<const float*>(yc);
        float d = (101.f * p[0] - 100.f * y[0] - 8.f) - (p[1] - prev2) * prev1;
        spi += d * d;
        d = (101.f * p[1] - 100.f * y[1] - 8.f) - (p[2] - prev1) * p[0];
        spi += d * d;
#pragma unroll
        for (int i = 2; i <= 18; ++i) {
            d = (101.f * p[i] - 100.f * y[i] - 8.f) - (p[i + 1] - p[i - 2]) * p[i - 1];
            spi += d * d;
        }
        d = (101.f * p[19] - 100.f * y[19] - 8.f) - (nxt - p[17]) * p[18];
        spi += d * d;
    }

    // Wave shuffle reduction in double -> LDS -> per-block partial.
    double sd = (double)sdd, sp = (double)spi;
#pragma unroll
    for (int off = 32; off > 0; off >>= 1) {
        sd += __shfl_down(sd, off, 64);
        sp += __shfl_down(sp, off, 64);
    }
    __shared__ double lds_red[2 * (BLOCK / 64)];
    const int lane = threadIdx.x & 63;
    const int wave = threadIdx.x >> 6;
    if (lane == 0) { lds_red[2 * wave] = sd; lds_red[2 * wave + 1] = sp; }
    __syncthreads();
    if (threadIdx.x == 0) {
        double tsd = 0.0, tsp = 0.0;
#pragma unroll
        for (int w = 0; w < BLOCK / 64; ++w) {
            tsd += lds_red[2 * w];
            tsp += lds_red[2 * w + 1];
        }
        partials[2 * blockIdx.x]     = tsd;   // every slot written every launch
        partials[2 * blockIdx.x + 1] = tsp;
    }
}

__global__ __launch_bounds__(256) void hybrid_loss_finalize(
    const double* __restrict__ partials, float* __restrict__ out)
{
    const double2* __restrict__ p2 = reinterpret_cast<const double2*>(partials);
    double sd = 0.0, sp = 0.0;
    for (int m = threadIdx.x; m < GRID; m += 256) {
        const double2 v = p2[m];
        sd += v.x; sp += v.y;
    }
#pragma unroll
    for (int off = 32; off > 0; off >>= 1) {
        sd += __shfl_down(sd, off, 64);
        sp += __shfl_down(sp, off, 64);
    }
    __shared__ double lds[8];
    const int lane = threadIdx.x & 63;
    const int wave = threadIdx.x >> 6;
    if (lane == 0) { lds[2 * wave] = sd; lds[2 * wave + 1] = sp; }
    __syncthreads();
    if (threadIdx.x == 0) {
        double tsd = 0.0, tsp = 0.0;
#pragma unroll
        for (int w = 0; w < 4; ++w) { tsd += lds[2 * w]; tsp += lds[2 * w + 1]; }
        const double l_dd = tsd / ((double)BATCH_L * NXL);
        const double l_pi = tsp / ((double)BATCH_L * NL);
        out[0] = (float)(l_dd + 0.1 * l_pi);
        out[1] = (float)l_dd;
        out[2] = (float)l_pi;
    }
}

extern "C" void kernel_launch(void* const* d_in, const int* in_sizes, int n_in,
                              void* d_out, int out_size, void* d_ws, size_t ws_size,
                              hipStream_t stream) {
    const float4* pred = (const float4*)d_in[0];
    const float4* targ = (const float4*)d_in[1];
    const float4* ycur = (const float4*)d_in[2];
    double* partials = (double*)d_ws;          // GRID * 2 doubles = 64 KB
    float* out = (float*)d_out;

    hybrid_loss_main<<<GRID, BLOCK, 0, stream>>>(pred, targ, ycur, partials);
    hybrid_loss_finalize<<<1, 256, 0, stream>>>(partials, out);
}